// Round 3
// baseline (135.311 us; speedup 1.0000x reference)
//
#include <hip/hip_runtime.h>
#include <hip/hip_cooperative_groups.h>
#include <math.h>

namespace cg = cooperative_groups;

#define B_ 64
#define S_ 24
#define E_ 128
#define G_ 256
#define N_ (B_ * S_)      // 1536
#define Km_ 100
#define Kch_ 200
#define Ko_ 50
#define Kp_ 50
#define Kc_ 30
#define TOTK_ 435         // 100+200+50+50+1+30+4

#define Vm_ 1000
#define Vch_ 3000
#define Vo_ 500
#define Vp_ 1500
#define Vl_ 700
#define Vc_ 2000
#define Vgen_ 2
#define Veth_ 10
#define Vins_ 5
#define Vage_ 100
#define TOTROWS_ 8817     // sum of all table rows

// rowmean buffer segment offsets (in floats)
#define OFF_MED 0
#define OFF_CHART 1000
#define OFF_OUT 4000
#define OFF_PROC 4500
#define OFF_LAB 6000
#define OFF_COND 6700
#define OFF_GEN 8700
#define OFF_ETH 8702
#define OFF_INS 8712
#define OFF_AGE 8717
#define OFF_MACC 8817     // macc[435] follows rowmeans in d_ws

#define NBLK_ 435
#define NTHR_ 512

__device__ __forceinline__ int clampi(int v, int hi) {
    return v < 0 ? 0 : (v > hi ? hi : v);
}

// ---------------------------------------------------------------------------
// Phase 1 body: one wave per embedding row -> rowmean over E=128
// ---------------------------------------------------------------------------
__device__ __forceinline__ void rowmeans_body(
    int wid, int lane, int stride,
    const float* __restrict__ medE, const float* __restrict__ chartE,
    const float* __restrict__ outE, const float* __restrict__ procE,
    const float* __restrict__ labE, const float* __restrict__ condE,
    const float* __restrict__ genE, const float* __restrict__ ethE,
    const float* __restrict__ insE, const float* __restrict__ ageE,
    float* __restrict__ rm)
{
    for (int row = wid; row < TOTROWS_; row += stride) {
        const float* src;
        int r = row;
        if (r < Vm_)                  { src = medE; }
        else if ((r -= Vm_)  < Vch_)  { src = chartE; }
        else if ((r -= Vch_) < Vo_)   { src = outE; }
        else if ((r -= Vo_)  < Vp_)   { src = procE; }
        else if ((r -= Vp_)  < Vl_)   { src = labE; }
        else if ((r -= Vl_)  < Vc_)   { src = condE; }
        else if ((r -= Vc_)  < Vgen_) { src = genE; }
        else if ((r -= Vgen_)< Veth_) { src = ethE; }
        else if ((r -= Veth_)< Vins_) { src = insE; }
        else                          { r -= Vins_; src = ageE; }

        float2 v = *reinterpret_cast<const float2*>(src + (size_t)r * E_ + lane * 2);
        float s = v.x + v.y;
        #pragma unroll
        for (int off = 32; off > 0; off >>= 1) s += __shfl_down(s, off, 64);
        if (lane == 0) rm[row] = s * (1.0f / E_);
    }
}

// ---------------------------------------------------------------------------
// Weight prefetch: blocks 0..63, 8 per XCD-group (blockIdx%8), each group
// collectively pulls all 740KB of head weights into its XCD's L2.
// ---------------------------------------------------------------------------
__device__ __forceinline__ void prefetch_body(
    int part, int t,
    const float* __restrict__ projW, const float* __restrict__ W1,
    const float* __restrict__ W2,   const float* __restrict__ fc1W)
{
    const float* arrs[4] = {projW, W1, W2, fc1W};
    const int n4s[4] = {TOTK_ * E_ / 4, E_ * G_ / 4, G_ * G_ / 4, G_ * (G_/2) / 4};
    float acc = 0.f;
    #pragma unroll
    for (int a = 0; a < 4; ++a) {
        const float4* p = (const float4*)arrs[a];
        const int n4 = n4s[a];
        const int chunk = (n4 + 7) >> 3;
        const int s0 = part * chunk;
        const int s1 = (s0 + chunk < n4) ? s0 + chunk : n4;
        for (int i = s0 + t; i < s1; i += NTHR_) {
            float4 v = p[i];
            acc += v.x + v.y + v.z + v.w;
        }
    }
    asm volatile("" : : "v"(acc));   // keep loads live (no DCE)
}

// ---------------------------------------------------------------------------
// Phase 2 body: block c computes macc[c] (deterministic gather-sum)
// ---------------------------------------------------------------------------
__device__ __forceinline__ void colsum_body(
    int c, int t,
    const int* __restrict__ meds, const int* __restrict__ chart,
    const int* __restrict__ outv, const int* __restrict__ proc,
    const int* __restrict__ lab,  const int* __restrict__ conds,
    const int* __restrict__ demo,
    const float* __restrict__ rm, float* __restrict__ macc)
{
    float s = 0.0f;
    float scale;

    if (c < 400) {
        const int* idx; int K, kk, base, vmax;
        if (c < Km_)             { idx = meds;  K = Km_;  kk = c;        base = OFF_MED;  vmax = Vm_ - 1; }
        else if (c < 300)        { idx = chart; K = Kch_; kk = c - 100;  base = OFF_CHART;vmax = Vch_ - 1; }
        else if (c < 350)        { idx = outv;  K = Ko_;  kk = c - 300;  base = OFF_OUT;  vmax = Vo_ - 1; }
        else                     { idx = proc;  K = Kp_;  kk = c - 350;  base = OFF_PROC; vmax = Vp_ - 1; }
        #pragma unroll
        for (int n = t; n < N_; n += NTHR_)
            s += rm[base + clampi(idx[n * K + kk], vmax)];
        scale = 1.0f / N_;
    } else if (c == 400) {
        #pragma unroll
        for (int n = t; n < N_; n += NTHR_)
            s += rm[OFF_LAB + clampi(lab[n], Vl_ - 1)];
        scale = 1.0f / N_;
    } else if (c < 431) {
        int kk = c - 401;
        for (int b = t; b < B_; b += NTHR_)
            s += rm[OFF_COND + clampi(conds[b * Kc_ + kk], Vc_ - 1)];
        scale = 1.0f / B_;
    } else {
        int j = c - 431;
        int base = (j == 0) ? OFF_GEN : (j == 1) ? OFF_ETH : (j == 2) ? OFF_INS : OFF_AGE;
        for (int b = t; b < B_; b += NTHR_)
            s += rm[base + demo[b * 4 + j]];
        scale = 1.0f / B_;
    }

    __shared__ float red[NTHR_];
    red[t] = s;
    __syncthreads();
    #pragma unroll
    for (int off = NTHR_ / 2; off > 0; off >>= 1) {
        if (t < off) red[t] += red[t + off];
        __syncthreads();
    }
    if (t == 0) macc[c] = red[0] * scale;
}

// ---------------------------------------------------------------------------
// Phase 3 body: whole MLP head, one block of 512 threads (8-way k-split per
// stage, float2/float4 loads). Entropy weight over identical rows == 1/N.
// ---------------------------------------------------------------------------
__device__ void head_body(
    const float* __restrict__ macc,
    const float* __restrict__ projW, const float* __restrict__ projb,
    const float* __restrict__ W1, const float* __restrict__ b1,
    const float* __restrict__ W2, const float* __restrict__ b2,
    const float* __restrict__ fc1W, const float* __restrict__ fc1b,
    const float* __restrict__ fc2W, const float* __restrict__ fc2b,
    float* __restrict__ outp)
{
    __shared__ float sm[TOTK_];
    __shared__ float xbar[E_];
    __shared__ float h1s[G_];
    __shared__ float h2s[G_];
    __shared__ float fsh[G_ / 2];
    __shared__ float4 part4[8][64];
    __shared__ float2 part2[8][64];
    __shared__ float hred[8];
    __shared__ float oval;

    const int t = threadIdx.x;
    const int lane = t & 63;
    const int oc = t >> 6;      // wave-group 0..7

    for (int i = t; i < TOTK_; i += NTHR_) sm[i] = macc[i];
    __syncthreads();

    // ---- xbar[128] = sm[435] @ projW[435,128] + projb : float2, 8-way
    {
        const float2* Wp = (const float2*)projW;   // [435][64]
        const int k0 = (TOTK_ * oc) >> 3;
        const int k1 = (TOTK_ * (oc + 1)) >> 3;
        float2 acc = {0.f, 0.f};
        #pragma unroll 8
        for (int k = k0; k < k1; ++k) {
            float s = sm[k];
            float2 w = Wp[k * 64 + lane];
            acc.x += s * w.x; acc.y += s * w.y;
        }
        part2[oc][lane] = acc;
        __syncthreads();
        if (t < 64) {
            float2 a = part2[0][t];
            #pragma unroll
            for (int j = 1; j < 8; ++j) { a.x += part2[j][t].x; a.y += part2[j][t].y; }
            xbar[2 * t]     = a.x + projb[2 * t];
            xbar[2 * t + 1] = a.y + projb[2 * t + 1];
        }
        __syncthreads();
    }

    // ---- h1[256] = relu(xbar @ W1[128,256] + b1) * (1/N) : float4, 8-way
    {
        const float4* Wp = (const float4*)W1;      // [128][64]
        const int k0 = oc * 16, k1 = k0 + 16;
        float4 acc = {0.f, 0.f, 0.f, 0.f};
        #pragma unroll 8
        for (int k = k0; k < k1; ++k) {
            float s = xbar[k];
            float4 w = Wp[k * 64 + lane];
            acc.x += s * w.x; acc.y += s * w.y; acc.z += s * w.z; acc.w += s * w.w;
        }
        part4[oc][lane] = acc;
        __syncthreads();
        if (t < 64) {
            float4 a = part4[0][t];
            #pragma unroll
            for (int j = 1; j < 8; ++j) {
                float4 p = part4[j][t];
                a.x += p.x; a.y += p.y; a.z += p.z; a.w += p.w;
            }
            float4 bb = ((const float4*)b1)[t];
            h1s[4 * t]     = fmaxf(a.x + bb.x, 0.f) * (1.0f / N_);
            h1s[4 * t + 1] = fmaxf(a.y + bb.y, 0.f) * (1.0f / N_);
            h1s[4 * t + 2] = fmaxf(a.z + bb.z, 0.f) * (1.0f / N_);
            h1s[4 * t + 3] = fmaxf(a.w + bb.w, 0.f) * (1.0f / N_);
        }
        __syncthreads();
    }

    // ---- h2[256] = h1 @ W2[256,256] + b2 : float4, 8-way
    {
        const float4* Wp = (const float4*)W2;      // [256][64]
        const int k0 = oc * 32, k1 = k0 + 32;
        float4 acc = {0.f, 0.f, 0.f, 0.f};
        #pragma unroll 8
        for (int k = k0; k < k1; ++k) {
            float s = h1s[k];
            float4 w = Wp[k * 64 + lane];
            acc.x += s * w.x; acc.y += s * w.y; acc.z += s * w.z; acc.w += s * w.w;
        }
        part4[oc][lane] = acc;
        __syncthreads();
        if (t < 64) {
            float4 a = part4[0][t];
            #pragma unroll
            for (int j = 1; j < 8; ++j) {
                float4 p = part4[j][t];
                a.x += p.x; a.y += p.y; a.z += p.z; a.w += p.w;
            }
            float4 bb = ((const float4*)b2)[t];
            h2s[4 * t]     = a.x + bb.x;
            h2s[4 * t + 1] = a.y + bb.y;
            h2s[4 * t + 2] = a.z + bb.z;
            h2s[4 * t + 3] = a.w + bb.w;
        }
        __syncthreads();
    }

    // ---- f[128] = relu(h2 @ fc1W[256,128] + fc1b) : float2, 8-way
    {
        const float2* Wp = (const float2*)fc1W;    // [256][64]
        const int k0 = oc * 32, k1 = k0 + 32;
        float2 acc = {0.f, 0.f};
        #pragma unroll 8
        for (int k = k0; k < k1; ++k) {
            float s = h2s[k];
            float2 w = Wp[k * 64 + lane];
            acc.x += s * w.x; acc.y += s * w.y;
        }
        part2[oc][lane] = acc;
        __syncthreads();
        if (t < 64) {
            float2 a = part2[0][t];
            #pragma unroll
            for (int j = 1; j < 8; ++j) { a.x += part2[j][t].x; a.y += part2[j][t].y; }
            fsh[2 * t]     = fmaxf(a.x + fc1b[2 * t], 0.f);
            fsh[2 * t + 1] = fmaxf(a.y + fc1b[2 * t + 1], 0.f);
        }
        __syncthreads();
    }

    // ---- o = f . fc2_W + fc2_b ; write outputs
    {
        float p = (t < G_ / 2) ? fsh[t] * fc2W[t] : 0.f;
        #pragma unroll
        for (int off = 32; off > 0; off >>= 1) p += __shfl_down(p, off, 64);
        if (lane == 0) hred[oc] = p;
        __syncthreads();
        if (t == 0) {
            float o = fc2b[0];
            #pragma unroll
            for (int j = 0; j < 8; ++j) o += hred[j];
            oval = o;
        }
        __syncthreads();
        const float o = oval;
        const float sig = 1.0f / (1.0f + expf(-o));
        if (t < B_)            outp[t] = sig;   // output 0: sigmoid(o)
        else if (t < 2 * B_)   outp[t] = o;     // output 1: o
    }
}

// ---------------------------------------------------------------------------
// Fused cooperative kernel: rowmeans+prefetch | gridsync | colsum | gridsync |
// head (block 0).
// ---------------------------------------------------------------------------
__global__ __launch_bounds__(NTHR_) void fused_kernel(
    const int* meds, const int* chart, const int* outv, const int* proc,
    const int* lab, const int* conds, const int* demo,
    const float* medE, const float* chartE, const float* outE,
    const float* procE, const float* labE, const float* condE,
    const float* genE, const float* ethE, const float* insE, const float* ageE,
    const float* projW, const float* projb, const float* W1, const float* b1,
    const float* W2, const float* b2, const float* fc1W, const float* fc1b,
    const float* fc2W, const float* fc2b,
    float* rm, float* macc, float* outp)
{
    const int t = threadIdx.x;

    // Phase 1: rowmeans (all blocks) + L2 weight prefetch (blocks 0..63)
    rowmeans_body(blockIdx.x * (NTHR_ / 64) + (t >> 6), t & 63,
                  gridDim.x * (NTHR_ / 64),
                  medE, chartE, outE, procE, labE, condE, genE, ethE, insE, ageE, rm);
    if (blockIdx.x < 64)
        prefetch_body(blockIdx.x >> 3, t, projW, W1, W2, fc1W);

    cg::this_grid().sync();

    // Phase 2: one column per block
    colsum_body(blockIdx.x, t, meds, chart, outv, proc, lab, conds, demo, rm, macc);

    cg::this_grid().sync();

    // Phase 3: head on block 0
    if (blockIdx.x == 0)
        head_body(macc, projW, projb, W1, b1, W2, b2, fc1W, fc1b, fc2W, fc2b, outp);
}

// ---------------------------------------------------------------------------
// Fallback kernels (identical math, 3 launches) in case cooperative launch
// is rejected by graph capture.
// ---------------------------------------------------------------------------
__global__ __launch_bounds__(NTHR_) void rowmeans_kernel(
    const float* medE, const float* chartE, const float* outE,
    const float* procE, const float* labE, const float* condE,
    const float* genE, const float* ethE, const float* insE, const float* ageE,
    float* rm)
{
    rowmeans_body(blockIdx.x * (NTHR_ / 64) + (threadIdx.x >> 6), threadIdx.x & 63,
                  gridDim.x * (NTHR_ / 64),
                  medE, chartE, outE, procE, labE, condE, genE, ethE, insE, ageE, rm);
}

__global__ __launch_bounds__(NTHR_) void colsum_kernel(
    const int* meds, const int* chart, const int* outv, const int* proc,
    const int* lab, const int* conds, const int* demo,
    const float* rm, float* macc)
{
    colsum_body(blockIdx.x, threadIdx.x, meds, chart, outv, proc, lab, conds, demo, rm, macc);
}

__global__ __launch_bounds__(NTHR_) void head_kernel(
    const float* macc,
    const float* projW, const float* projb, const float* W1, const float* b1,
    const float* W2, const float* b2, const float* fc1W, const float* fc1b,
    const float* fc2W, const float* fc2b, float* outp)
{
    head_body(macc, projW, projb, W1, b1, W2, b2, fc1W, fc1b, fc2W, fc2b, outp);
}

// ---------------------------------------------------------------------------
extern "C" void kernel_launch(void* const* d_in, const int* in_sizes, int n_in,
                              void* d_out, int out_size, void* d_ws, size_t ws_size,
                              hipStream_t stream) {
    const int* meds  = (const int*)d_in[0];
    const int* chart = (const int*)d_in[1];
    const int* outv  = (const int*)d_in[2];
    const int* proc  = (const int*)d_in[3];
    const int* lab   = (const int*)d_in[4];
    const int* conds = (const int*)d_in[5];
    const int* demo  = (const int*)d_in[6];
    const float* medE   = (const float*)d_in[7];
    const float* chartE = (const float*)d_in[8];
    const float* outE   = (const float*)d_in[9];
    const float* procE  = (const float*)d_in[10];
    const float* labE   = (const float*)d_in[11];
    const float* condE  = (const float*)d_in[12];
    const float* genE   = (const float*)d_in[13];
    const float* ethE   = (const float*)d_in[14];
    const float* insE   = (const float*)d_in[15];
    const float* ageE   = (const float*)d_in[16];
    const float* projW  = (const float*)d_in[17];
    const float* projb  = (const float*)d_in[18];
    const float* W1     = (const float*)d_in[19];
    const float* b1     = (const float*)d_in[20];
    const float* W2     = (const float*)d_in[21];
    const float* b2     = (const float*)d_in[22];
    const float* fc1W   = (const float*)d_in[23];
    const float* fc1b   = (const float*)d_in[24];
    const float* fc2W   = (const float*)d_in[25];
    const float* fc2b   = (const float*)d_in[26];

    float* rm   = (float*)d_ws;          // 8817 floats
    float* macc = rm + OFF_MACC;         // 435 floats
    float* outp = (float*)d_out;         // 128 floats

    void* kargs[] = {
        (void*)&meds, (void*)&chart, (void*)&outv, (void*)&proc,
        (void*)&lab, (void*)&conds, (void*)&demo,
        (void*)&medE, (void*)&chartE, (void*)&outE, (void*)&procE,
        (void*)&labE, (void*)&condE, (void*)&genE, (void*)&ethE,
        (void*)&insE, (void*)&ageE,
        (void*)&projW, (void*)&projb, (void*)&W1, (void*)&b1,
        (void*)&W2, (void*)&b2, (void*)&fc1W, (void*)&fc1b,
        (void*)&fc2W, (void*)&fc2b,
        (void*)&rm, (void*)&macc, (void*)&outp
    };

    hipError_t err = hipLaunchCooperativeKernel(
        (const void*)fused_kernel, dim3(NBLK_), dim3(NTHR_), kargs, 0, stream);

    if (err != hipSuccess) {
        // Fallback: 3 ordinary launches (same math).
        int blocksA = (TOTROWS_ + (NTHR_ / 64) - 1) / (NTHR_ / 64);
        rowmeans_kernel<<<blocksA, NTHR_, 0, stream>>>(
            medE, chartE, outE, procE, labE, condE, genE, ethE, insE, ageE, rm);
        colsum_kernel<<<NBLK_, NTHR_, 0, stream>>>(
            meds, chart, outv, proc, lab, conds, demo, rm, macc);
        head_kernel<<<1, NTHR_, 0, stream>>>(
            macc, projW, projb, W1, b1, W2, b2, fc1W, fc1b, fc2W, fc2b, outp);
    }
}

// Round 4
// 38.624 us; speedup vs baseline: 3.5033x; 3.5033x over previous
//
#include <hip/hip_runtime.h>
#include <math.h>

#define B_ 64
#define S_ 24
#define E_ 128
#define G_ 256
#define N_ (B_ * S_)      // 1536
#define Km_ 100
#define Kch_ 200
#define Ko_ 50
#define Kp_ 50
#define Kc_ 30
#define TOTK_ 435         // 100+200+50+50+1+30+4

#define Vm_ 1000
#define Vch_ 3000
#define Vo_ 500
#define Vp_ 1500
#define Vl_ 700
#define Vc_ 2000
#define TOTROWS_ 8817     // sum of all table rows

// rowmean buffer segment offsets (floats, in d_ws)
#define OFF_MED 0
#define OFF_CHART 1000
#define OFF_OUT 4000
#define OFF_PROC 4500
#define OFF_LAB 6000
#define OFF_COND 6700
#define OFF_GEN 8700
#define OFF_ETH 8702
#define OFF_INS 8712
#define OFF_AGE 8717
// ws layout after rm[8817]:
#define OFF_CTR 8824      // int counter (4-aligned), reset by kernel A
#define OFF_PART 8832     // part[TOTK_][16] floats (16B-aligned: 8832*4 % 16 == 0)

#define NCHUNK_ 16        // n-chunks per big table
#define CHUNK_N_ 96       // 1536 / 16
#define NBLK_B_ 65        // 64 table-chunk blocks + 1 small block
#define NTHR_ 512

__device__ __forceinline__ int clampi(int v, int hi) {
    return v < 0 ? 0 : (v > hi ? hi : v);
}

// ---------------------------------------------------------------------------
// Kernel A: one wave per embedding row -> rowmean over E=128. Block 0 also
// resets the completion counter for kernel B (visible at kernel boundary).
// ---------------------------------------------------------------------------
__global__ __launch_bounds__(NTHR_) void rowmeans_kernel(
    const float* __restrict__ medE, const float* __restrict__ chartE,
    const float* __restrict__ outE, const float* __restrict__ procE,
    const float* __restrict__ labE, const float* __restrict__ condE,
    const float* __restrict__ genE, const float* __restrict__ ethE,
    const float* __restrict__ insE, const float* __restrict__ ageE,
    float* __restrict__ rm, int* __restrict__ ctr)
{
    if (blockIdx.x == 0 && threadIdx.x == 0) *ctr = 0;

    int row = blockIdx.x * (NTHR_ / 64) + (threadIdx.x >> 6);
    int lane = threadIdx.x & 63;
    if (row >= TOTROWS_) return;

    const float* src;
    int r = row;
    if (r < Vm_)                  { src = medE; }
    else if ((r -= Vm_)  < Vch_)  { src = chartE; }
    else if ((r -= Vch_) < Vo_)   { src = outE; }
    else if ((r -= Vo_)  < Vp_)   { src = procE; }
    else if ((r -= Vp_)  < Vl_)   { src = labE; }
    else if ((r -= Vl_)  < Vc_)   { src = condE; }
    else if ((r -= Vc_)  < 2)     { src = genE; }
    else if ((r -= 2)    < 10)    { src = ethE; }
    else if ((r -= 10)   < 5)     { src = insE; }
    else                          { r -= 5; src = ageE; }

    float2 v = *reinterpret_cast<const float2*>(src + (size_t)r * E_ + lane * 2);
    float s = v.x + v.y;
    #pragma unroll
    for (int off = 32; off > 0; off >>= 1) s += __shfl_down(s, off, 64);
    if (lane == 0) rm[row] = s * (1.0f / E_);
}

// ---------------------------------------------------------------------------
// Coalesced per-table chunk colsum: threads map to (row-in-group, column) so
// idx loads are contiguous; per-column partial -> part[c][chunk].
// ---------------------------------------------------------------------------
template<int K, int RPI, int CBASE, int RMBASE, int VMAX>
__device__ __forceinline__ void table_chunk(
    const int* __restrict__ idx, const float* __restrict__ rm,
    float* __restrict__ part, int p, int t, float* __restrict__ lds)
{
    constexpr int ACT = K * RPI;
    float acc = 0.0f;
    if (t < ACT) {
        const int kk = t % K;
        const int nr = t / K;
        const int n0 = p * CHUNK_N_;
        for (int n = n0 + nr; n < n0 + CHUNK_N_; n += RPI) {
            int ix = clampi(idx[n * K + kk], VMAX);
            acc += rm[RMBASE + ix];
        }
    }
    lds[t] = acc;
    __syncthreads();
    if (t < K) {
        float s = lds[t];
        #pragma unroll
        for (int r = 1; r < RPI; ++r) s += lds[r * K + t];
        part[(CBASE + t) * NCHUNK_ + p] = s;   // raw sum; scaled in head
    }
}

// ---------------------------------------------------------------------------
// Head: sums the 16 partials per column (fixed order), scales, then runs the
// 4-stage MLP chain 8-way k-split. Entropy weight over identical rows == 1/N.
// ---------------------------------------------------------------------------
__device__ void head_body(
    const float* __restrict__ part,
    const float* __restrict__ projW, const float* __restrict__ projb,
    const float* __restrict__ W1, const float* __restrict__ b1,
    const float* __restrict__ W2, const float* __restrict__ b2,
    const float* __restrict__ fc1W, const float* __restrict__ fc1b,
    const float* __restrict__ fc2W, const float* __restrict__ fc2b,
    float* __restrict__ outp)
{
    __shared__ float sm[TOTK_];
    __shared__ float xbar[E_];
    __shared__ float h1s[G_];
    __shared__ float h2s[G_];
    __shared__ float fsh[G_ / 2];
    __shared__ float4 part4[8][64];
    __shared__ float2 part2[8][64];
    __shared__ float hred[8];
    __shared__ float oval;

    const int t = threadIdx.x;
    const int lane = t & 63;
    const int oc = t >> 6;      // wave-group 0..7

    // ---- partial-sum stage: sm[k] = scale * sum_p part[k][p]
    if (t < TOTK_) {
        const float4* pp = (const float4*)(part + t * NCHUNK_);
        float s;
        if (t < 400) {
            float4 a = pp[0], b = pp[1], c = pp[2], d = pp[3];
            s = (((a.x + a.y) + (a.z + a.w)) + ((b.x + b.y) + (b.z + b.w)))
              + (((c.x + c.y) + (c.z + c.w)) + ((d.x + d.y) + (d.z + d.w)));
            s *= (1.0f / N_);
        } else if (t == 400) {
            s = part[t * NCHUNK_] * (1.0f / N_);
        } else {
            s = part[t * NCHUNK_] * (1.0f / B_);
        }
        sm[t] = s;
    }
    __syncthreads();

    // ---- xbar[128] = sm[435] @ projW[435,128] + projb : float2, 8-way
    {
        const float2* Wp = (const float2*)projW;   // [435][64]
        const int k0 = (TOTK_ * oc) >> 3;
        const int k1 = (TOTK_ * (oc + 1)) >> 3;
        float2 acc = {0.f, 0.f};
        #pragma unroll 8
        for (int k = k0; k < k1; ++k) {
            float s = sm[k];
            float2 w = Wp[k * 64 + lane];
            acc.x += s * w.x; acc.y += s * w.y;
        }
        part2[oc][lane] = acc;
        __syncthreads();
        if (t < 64) {
            float2 a = part2[0][t];
            #pragma unroll
            for (int j = 1; j < 8; ++j) { a.x += part2[j][t].x; a.y += part2[j][t].y; }
            xbar[2 * t]     = a.x + projb[2 * t];
            xbar[2 * t + 1] = a.y + projb[2 * t + 1];
        }
        __syncthreads();
    }

    // ---- h1[256] = relu(xbar @ W1[128,256] + b1) * (1/N) : float4, 8-way
    {
        const float4* Wp = (const float4*)W1;      // [128][64]
        const int k0 = oc * 16, k1 = k0 + 16;
        float4 acc = {0.f, 0.f, 0.f, 0.f};
        #pragma unroll 8
        for (int k = k0; k < k1; ++k) {
            float s = xbar[k];
            float4 w = Wp[k * 64 + lane];
            acc.x += s * w.x; acc.y += s * w.y; acc.z += s * w.z; acc.w += s * w.w;
        }
        part4[oc][lane] = acc;
        __syncthreads();
        if (t < 64) {
            float4 a = part4[0][t];
            #pragma unroll
            for (int j = 1; j < 8; ++j) {
                float4 p = part4[j][t];
                a.x += p.x; a.y += p.y; a.z += p.z; a.w += p.w;
            }
            float4 bb = ((const float4*)b1)[t];
            h1s[4 * t]     = fmaxf(a.x + bb.x, 0.f) * (1.0f / N_);
            h1s[4 * t + 1] = fmaxf(a.y + bb.y, 0.f) * (1.0f / N_);
            h1s[4 * t + 2] = fmaxf(a.z + bb.z, 0.f) * (1.0f / N_);
            h1s[4 * t + 3] = fmaxf(a.w + bb.w, 0.f) * (1.0f / N_);
        }
        __syncthreads();
    }

    // ---- h2[256] = h1 @ W2[256,256] + b2 : float4, 8-way
    {
        const float4* Wp = (const float4*)W2;      // [256][64]
        const int k0 = oc * 32, k1 = k0 + 32;
        float4 acc = {0.f, 0.f, 0.f, 0.f};
        #pragma unroll 8
        for (int k = k0; k < k1; ++k) {
            float s = h1s[k];
            float4 w = Wp[k * 64 + lane];
            acc.x += s * w.x; acc.y += s * w.y; acc.z += s * w.z; acc.w += s * w.w;
        }
        part4[oc][lane] = acc;
        __syncthreads();
        if (t < 64) {
            float4 a = part4[0][t];
            #pragma unroll
            for (int j = 1; j < 8; ++j) {
                float4 p = part4[j][t];
                a.x += p.x; a.y += p.y; a.z += p.z; a.w += p.w;
            }
            float4 bb = ((const float4*)b2)[t];
            h2s[4 * t]     = a.x + bb.x;
            h2s[4 * t + 1] = a.y + bb.y;
            h2s[4 * t + 2] = a.z + bb.z;
            h2s[4 * t + 3] = a.w + bb.w;
        }
        __syncthreads();
    }

    // ---- f[128] = relu(h2 @ fc1W[256,128] + fc1b) : float2, 8-way
    {
        const float2* Wp = (const float2*)fc1W;    // [256][64]
        const int k0 = oc * 32, k1 = k0 + 32;
        float2 acc = {0.f, 0.f};
        #pragma unroll 8
        for (int k = k0; k < k1; ++k) {
            float s = h2s[k];
            float2 w = Wp[k * 64 + lane];
            acc.x += s * w.x; acc.y += s * w.y;
        }
        part2[oc][lane] = acc;
        __syncthreads();
        if (t < 64) {
            float2 a = part2[0][t];
            #pragma unroll
            for (int j = 1; j < 8; ++j) { a.x += part2[j][t].x; a.y += part2[j][t].y; }
            fsh[2 * t]     = fmaxf(a.x + fc1b[2 * t], 0.f);
            fsh[2 * t + 1] = fmaxf(a.y + fc1b[2 * t + 1], 0.f);
        }
        __syncthreads();
    }

    // ---- o = f . fc2_W + fc2_b ; write outputs
    {
        float p = (t < G_ / 2) ? fsh[t] * fc2W[t] : 0.f;
        #pragma unroll
        for (int off = 32; off > 0; off >>= 1) p += __shfl_down(p, off, 64);
        if (lane == 0) hred[oc] = p;
        __syncthreads();
        if (t == 0) {
            float o = fc2b[0];
            #pragma unroll
            for (int j = 0; j < 8; ++j) o += hred[j];
            oval = o;
        }
        __syncthreads();
        const float o = oval;
        const float sig = 1.0f / (1.0f + expf(-o));
        if (t < B_)            outp[t] = sig;   // output 0: sigmoid(o)
        else if (t < 2 * B_)   outp[t] = o;     // output 1: o
    }
}

// ---------------------------------------------------------------------------
// Kernel B: 65 blocks. Blocks 0..63 = (table = bid/16, chunk = bid%16) with
// coalesced idx loads; block 64 = lab/conds/demo via wave reductions. The
// last block to finish (counter) runs the head (rocPRIM last-block pattern).
// ---------------------------------------------------------------------------
__global__ __launch_bounds__(NTHR_) void colsum_head_kernel(
    const int* __restrict__ meds, const int* __restrict__ chart,
    const int* __restrict__ outv, const int* __restrict__ proc,
    const int* __restrict__ lab,  const int* __restrict__ conds,
    const int* __restrict__ demo,
    const float* __restrict__ rm, float* __restrict__ part, int* __restrict__ ctr,
    const float* __restrict__ projW, const float* __restrict__ projb,
    const float* __restrict__ W1, const float* __restrict__ b1,
    const float* __restrict__ W2, const float* __restrict__ b2,
    const float* __restrict__ fc1W, const float* __restrict__ fc1b,
    const float* __restrict__ fc2W, const float* __restrict__ fc2b,
    float* __restrict__ outp)
{
    __shared__ float lds_red[NTHR_];
    __shared__ int s_old;

    const int t = threadIdx.x;
    const int bid = blockIdx.x;

    if (bid < 64) {
        const int table = bid >> 4;
        const int p = bid & 15;
        if (table == 0)      table_chunk<Km_, 5, 0,   OFF_MED,  Vm_ -1>(meds,  rm, part, p, t, lds_red);
        else if (table == 1) table_chunk<Kch_,2, 100, OFF_CHART,Vch_-1>(chart, rm, part, p, t, lds_red);
        else if (table == 2) table_chunk<Ko_, 10,300, OFF_OUT,  Vo_ -1>(outv,  rm, part, p, t, lds_red);
        else                 table_chunk<Kp_, 10,350, OFF_PROC, Vp_ -1>(proc,  rm, part, p, t, lds_red);
    } else {
        // small block: 35 columns (lab, conds x30, demo x4), one per wave slot
        const int lane = t & 63;
        const int w = t >> 6;
        for (int j = w; j < 35; j += 8) {
            float s = 0.0f;
            if (j == 0) {
                #pragma unroll
                for (int i = 0; i < 24; ++i)
                    s += rm[OFF_LAB + clampi(lab[lane + 64 * i], Vl_ - 1)];
            } else if (j < 31) {
                int kk = j - 1;
                s = rm[OFF_COND + clampi(conds[lane * Kc_ + kk], Vc_ - 1)];
            } else {
                int jj = j - 31;
                int base = (jj == 0) ? OFF_GEN : (jj == 1) ? OFF_ETH :
                           (jj == 2) ? OFF_INS : OFF_AGE;
                s = rm[base + demo[lane * 4 + jj]];
            }
            #pragma unroll
            for (int off = 32; off > 0; off >>= 1) s += __shfl_down(s, off, 64);
            if (lane == 0) part[(400 + j) * NCHUNK_] = s;
        }
    }

    // last-block-done: winner runs the head
    __threadfence();
    __syncthreads();
    if (t == 0) s_old = atomicAdd(ctr, 1);
    __syncthreads();
    if (s_old == NBLK_B_ - 1) {
        __threadfence();
        head_body(part, projW, projb, W1, b1, W2, b2,
                  fc1W, fc1b, fc2W, fc2b, outp);
    }
}

// ---------------------------------------------------------------------------
extern "C" void kernel_launch(void* const* d_in, const int* in_sizes, int n_in,
                              void* d_out, int out_size, void* d_ws, size_t ws_size,
                              hipStream_t stream) {
    const int* meds  = (const int*)d_in[0];
    const int* chart = (const int*)d_in[1];
    const int* outv  = (const int*)d_in[2];
    const int* proc  = (const int*)d_in[3];
    const int* lab   = (const int*)d_in[4];
    const int* conds = (const int*)d_in[5];
    const int* demo  = (const int*)d_in[6];
    const float* medE   = (const float*)d_in[7];
    const float* chartE = (const float*)d_in[8];
    const float* outE   = (const float*)d_in[9];
    const float* procE  = (const float*)d_in[10];
    const float* labE   = (const float*)d_in[11];
    const float* condE  = (const float*)d_in[12];
    const float* genE   = (const float*)d_in[13];
    const float* ethE   = (const float*)d_in[14];
    const float* insE   = (const float*)d_in[15];
    const float* ageE   = (const float*)d_in[16];
    const float* projW  = (const float*)d_in[17];
    const float* projb  = (const float*)d_in[18];
    const float* W1     = (const float*)d_in[19];
    const float* b1     = (const float*)d_in[20];
    const float* W2     = (const float*)d_in[21];
    const float* b2     = (const float*)d_in[22];
    const float* fc1W   = (const float*)d_in[23];
    const float* fc1b   = (const float*)d_in[24];
    const float* fc2W   = (const float*)d_in[25];
    const float* fc2b   = (const float*)d_in[26];

    float* rm   = (float*)d_ws;                 // rm[8817]
    int*   ctr  = (int*)d_ws + OFF_CTR;         // completion counter
    float* part = (float*)d_ws + OFF_PART;      // part[435][16]
    float* outp = (float*)d_out;                // 128 floats

    // A: row means (+ counter reset)
    int blocksA = (TOTROWS_ + (NTHR_ / 64) - 1) / (NTHR_ / 64);
    rowmeans_kernel<<<blocksA, NTHR_, 0, stream>>>(
        medE, chartE, outE, procE, labE, condE, genE, ethE, insE, ageE, rm, ctr);

    // B: coalesced colsum partials + last-block head
    colsum_head_kernel<<<NBLK_B_, NTHR_, 0, stream>>>(
        meds, chart, outv, proc, lab, conds, demo, rm, part, ctr,
        projW, projb, W1, b1, W2, b2, fc1W, fc1b, fc2W, fc2b, outp);
}